// Round 4
// baseline (653.923 us; speedup 1.0000x reference)
//
#include <hip/hip_runtime.h>
#include <cmath>

// ConvLSTM2D forward, bf16 MFMA implicit GEMM, R9: LDS-free single-round kernel.
// B=8, T=16, H=W=96, Cin=8, F=64 (4F=256 gates), 3x3 SAME, 16 sequential steps.
// Per step GEMM: M=73728, N=256, K=672 (21 K-steps of 32: 18 h + 3 packed x).
// R8 post-mortem: barrier/LDS removal was NEUTRAL (588us both) -> latency-bound
// at 1.5 scheduling rounds (1536 blocks, 4/CU) with long wave lifetimes.
// R9: wave M=96 (6 rows x 16 cols), block M=384 -> grid 768 = EXACTLY 3 blocks/CU,
// one scheduling round, no tail. No LDS, no __syncthreads: A-fragments gather
// straight global->VGPR (q=0/1 lanes cover complementary 16B halves of the 32B
// h-granules -> fully coalesced 512B segments, L1/L3-resident), 8-slot register
// window slides over dy; B fragments global->VGPR from the L2-resident slab
// stream. OOB halo reads select a zeroed global buffer. VGPR ~155 <= 168 (3/SIMD).

#define HTOT 96
#define WTOT 96
#define CINX 8
#define FF   64
#define G4   256
#define BB   8
#define TT   16
#define NPOS (BB*HTOT*WTOT)        // 73728 global positions

typedef __attribute__((ext_vector_type(8))) short short8;   // 8 bf16 = 4 VGPRs
typedef __attribute__((ext_vector_type(4))) float floatx4;

union U16 { uint4 u; short8 s; };

__device__ __forceinline__ float hsig(float z) {
    return fminf(fmaxf(0.2f * z + 0.5f, 0.f), 1.f);
}

__device__ __forceinline__ float ftanh(float x) {
    float e = __expf(-2.f * fabsf(x));
    float t = (1.f - e) / (1.f + e);
    return copysignf(t, x);
}

__device__ __forceinline__ ushort f2bf(float f) {            // RNE fp32->bf16
    unsigned u = __float_as_uint(f);
    u = (u + 0x7fff + ((u >> 16) & 1)) >> 16;
    return (ushort)u;
}

// ---- prep: x fp32 -> bf16 (all T at once), layout [b,t,y,x,8] ----
__global__ __launch_bounds__(256) void conv_x_bf16(const float* __restrict__ x,
                                                   ushort* __restrict__ xbf, int n4) {
    int i = blockIdx.x * 256 + threadIdx.x;
    if (i >= n4) return;
    float4 v = ((const float4*)x)[i];
    ushort4 o;
    o.x = f2bf(v.x); o.y = f2bf(v.y); o.z = f2bf(v.z); o.w = f2bf(v.w);
    ((ushort4*)xbf)[i] = o;
}

// ---- prep: weights -> per-slice slab stream, slab s order = dx*6 + kh*3 + dy ----
// Bp[(slice*21+s)*256 + g*64 + lane] (16B units); lane(q,col) holds B rows q*8..q*8+7
__global__ __launch_bounds__(256) void prep_w(const float* __restrict__ Wx,
                                              const float* __restrict__ Wh,
                                              ushort* __restrict__ Bp) {
    int idx = blockIdx.x * 256 + threadIdx.x;
    if (idx >= 4 * 21 * 256) return;                 // 21504
    int lane = idx & 63;
    int g = (idx >> 6) & 3;
    int rest = idx >> 8;                             // slice*21 + s
    int s = rest % 21, slice = rest / 21;
    int q = lane >> 4, col = lane & 15;
    int n = g * 64 + slice * 16 + col;
    ushort o[8];
    if (s < 18) {
        int dxw = s / 6, rem = s - 6 * dxw;
        int khw = rem / 3, dyw = rem - 3 * khw;
        int tap = dyw * 3 + dxw;
        int cbase = khw * 32 + q * 8;
        #pragma unroll
        for (int j = 0; j < 8; ++j)
            o[j] = f2bf(Wh[((size_t)tap * FF + cbase + j) * G4 + n]);
    } else {
        int tap = (s - 18) * 4 + q;                  // packed x-taps; >8 -> zero pad
        #pragma unroll
        for (int j = 0; j < 8; ++j)
            o[j] = (tap < 9) ? f2bf(Wx[((size_t)tap * CINX + j) * G4 + n]) : (ushort)0;
    }
    U16 u;
    #pragma unroll
    for (int j = 0; j < 8; ++j) ((ushort*)&u)[j] = o[j];
    ((uint4*)Bp)[idx] = u.u;
}

// ---- main step kernel: no LDS, no barriers ----
__global__ __launch_bounds__(256, 3) void convlstm_mfma(
    const ushort* __restrict__ xbf, int t,
    const ushort* __restrict__ hS_in,     // [s8][pos][8] bf16 pairs ([slice][pos][16])
    ushort* __restrict__ hS_out,
    float* __restrict__ cS,               // [slice][pos][16] fp32
    const ushort* __restrict__ Bp,
    const float* __restrict__ bias,
    const uint4* __restrict__ zpad,       // 64B of zeros for OOB halo reads
    float* __restrict__ out, int last)
{
    const int tid = threadIdx.x;
    const int x0 = blockIdx.x * 16, y0 = blockIdx.y * 24;
    const int bb = blockIdx.z >> 2, slice = blockIdx.z & 3;
    const int w = tid >> 6, lane = tid & 63, q = lane >> 4, col = lane & 15;
    const int rowb = w * 6;                          // wave rows rowb..rowb+5 (of 24)

    // per-lane B pointer: fragment (s,g) at gB[s*256 + g*64]; 1KB contiguous/wave
    const uint4* gB = (const uint4*)Bp + (size_t)(slice * 21) * 256 + lane;

    // h gather geometry: window row j -> gy = gyb+j; col shift dx -> gx = gxl+dx
    // fragment = 16B at ushort offset ((s8*NPOS+gpos)*16 + (q&1)*8), s8 = kh*2+(q>>1)
    const int gyb = y0 + rowb - 1;
    const int gxl = x0 - 1 + col;
    const long hb0 = ((long)(q >> 1) * NPOS) * 16 + (q & 1) * 8
                   + ((long)(bb * HTOT + gyb) * WTOT + gxl) * 16;
    const long xb0 = (((long)(bb * TT + t) * HTOT + gyb) * WTOT + gxl) * 8;

    floatx4 acc[6][4];
    #pragma unroll
    for (int g = 0; g < 4; ++g) {
        float bv = bias[g * 64 + slice * 16 + col];
        #pragma unroll
        for (int mt = 0; mt < 6; ++mt) acc[mt][g] = (floatx4){bv, bv, bv, bv};
    }

    // ---- h phase: s = dx*6 + kh*3 + dy; 8-slot A register window over dy ----
    U16 aw[8];
    #pragma unroll
    for (int dx = 0; dx < 3; ++dx) {
        const bool okx = ((unsigned)(gxl + dx) < (unsigned)WTOT);
        #pragma unroll
        for (int kh = 0; kh < 2; ++kh) {
            #pragma unroll
            for (int j = 0; j < 6; ++j) {            // prime rows 0..5
                bool ok = okx && ((unsigned)(gyb + j) < (unsigned)HTOT);
                const ushort* p = hS_in + hb0 + (long)kh * (2L * NPOS * 16)
                                + j * (WTOT * 16) + dx * 16;
                aw[j].u = *(ok ? (const uint4*)p : zpad);
            }
            #pragma unroll
            for (int dy = 0; dy < 3; ++dy) {
                const int s = dx * 6 + kh * 3 + dy;
                if (dy) {                            // slide: row 5+dy -> slot 5+dy
                    const int j = 5 + dy;
                    bool ok = okx && ((unsigned)(gyb + j) < (unsigned)HTOT);
                    const ushort* p = hS_in + hb0 + (long)kh * (2L * NPOS * 16)
                                    + j * (WTOT * 16) + dx * 16;
                    aw[j].u = *(ok ? (const uint4*)p : zpad);
                }
                U16 b4[4];
                #pragma unroll
                for (int g = 0; g < 4; ++g) b4[g].u = gB[s * 256 + g * 64];
                #pragma unroll
                for (int g = 0; g < 4; ++g)
                    #pragma unroll
                    for (int mt = 0; mt < 6; ++mt)
                        acc[mt][g] = __builtin_amdgcn_mfma_f32_16x16x32_bf16(
                            aw[mt + dy].s, b4[g].s, acc[mt][g], 0, 0, 0);
            }
        }
    }

    // ---- x phase: s = 18,19,20; packed taps (tap = sx*4+q, B rows 0 for pad) ----
    #pragma unroll
    for (int sx = 0; sx < 3; ++sx) {
        const int s = 18 + sx;
        int tap = sx * 4 + q; if (tap > 8) tap = 8;
        int dyq = tap / 3, dxq = tap - 3 * dyq;
        const bool okxq = ((unsigned)(gxl + dxq) < (unsigned)WTOT);
        U16 b4[4], a4[6];
        #pragma unroll
        for (int g = 0; g < 4; ++g) b4[g].u = gB[s * 256 + g * 64];
        #pragma unroll
        for (int mt = 0; mt < 6; ++mt) {
            int jj = mt + dyq;
            bool ok = okxq && ((unsigned)(gyb + jj) < (unsigned)HTOT);
            const ushort* p = xbf + xb0 + jj * (WTOT * 8) + dxq * 8;
            a4[mt].u = *(ok ? (const uint4*)p : zpad);
        }
        #pragma unroll
        for (int g = 0; g < 4; ++g)
            #pragma unroll
            for (int mt = 0; mt < 6; ++mt)
                acc[mt][g] = __builtin_amdgcn_mfma_f32_16x16x32_bf16(
                    a4[mt].s, b4[g].s, acc[mt][g], 0, 0, 0);
    }

    // ---- epilogue: gates fused in-register; contiguous slice-major writes ----
    #pragma unroll
    for (int mt = 0; mt < 6; ++mt) {
        int gy = y0 + rowb + mt;
        #pragma unroll
        for (int r = 0; r < 4; ++r) {
            int gx = x0 + q * 4 + r;
            size_t gpos = ((size_t)bb * HTOT + gy) * WTOT + gx;
            size_t idx = ((size_t)slice * NPOS + gpos) * 16 + col;
            float zi = acc[mt][0][r], zf = acc[mt][1][r];
            float zg = acc[mt][2][r], zo = acc[mt][3][r];
            float cn = hsig(zf) * cS[idx] + hsig(zi) * ftanh(zg);
            cS[idx] = cn;
            float hn = hsig(zo) * ftanh(cn);
            hS_out[idx] = f2bf(hn);
            if (last) out[gpos * 64 + slice * 16 + col] = hn;
        }
    }
}

extern "C" void kernel_launch(void* const* d_in, const int* in_sizes, int n_in,
                              void* d_out, int out_size, void* d_ws, size_t ws_size,
                              hipStream_t stream) {
    const float* x  = (const float*)d_in[0];
    const float* Wx = (const float*)d_in[1];
    const float* Wh = (const float*)d_in[2];
    const float* b  = (const float*)d_in[3];

    const size_t NX = (size_t)BB * TT * HTOT * WTOT * CINX;  // 9,437,184
    const size_t NH = (size_t)NPOS * FF;                     // 4,718,592

    char* ws = (char*)d_ws;
    ushort* xbf = (ushort*)ws;                  ws += NX * 2;            // 18.9 MB
    ushort* hS0 = (ushort*)ws;                  ws += NH * 2;            //  9.4 MB
    ushort* hS1 = (ushort*)ws;                  ws += NH * 2;            //  9.4 MB
    float*  cS  = (float*)ws;                   ws += NH * 4;            // 18.9 MB
    ushort* Bp  = (ushort*)ws;                  ws += (size_t)4*21*256*16; // 344 KB
    uint4*  zpad = (uint4*)ws;                                           // 64 B zeros

    hipMemsetAsync(hS0, 0, NH * 2, stream);
    hipMemsetAsync(cS,  0, NH * 4, stream);
    hipMemsetAsync(zpad, 0, 64, stream);

    conv_x_bf16<<<(int)((NX / 4 + 255) / 256), 256, 0, stream>>>(x, xbf, (int)(NX / 4));
    prep_w<<<(4 * 21 * 256 + 255) / 256, 256, 0, stream>>>(Wx, Wh, Bp);

    dim3 grid(WTOT / 16, HTOT / 24, BB * 4);     // 6 x 4 x 32 = 768 blocks
    for (int t = 0; t < TT; ++t) {
        const ushort* hin = (t & 1) ? hS1 : hS0;
        ushort* hout      = (t & 1) ? hS0 : hS1;
        convlstm_mfma<<<grid, 256, 0, stream>>>(xbf, t, hin, hout, cS, Bp, b, zpad,
                                                (float*)d_out, t == TT - 1);
    }
}